// Round 2
// baseline (327.392 us; speedup 1.0000x reference)
//
#include <hip/hip_runtime.h>
#include <hip/hip_fp16.h>

typedef unsigned int uint;
typedef unsigned short ushort;

typedef __attribute__((ext_vector_type(8))) _Float16 f16x8;
typedef __attribute__((ext_vector_type(4))) float f32x4;

#define TOK 256
#define OUTF 11008
#define INF 4096
#define BM 256
#define BN 64
#define NT2 172  // OUTF / BN

__device__ __constant__ float NF4_TBL[16] = {
    -1.0f, -0.6961928009986877f, -0.5250730514526367f, -0.39491748809814453f,
    -0.28444138169288635f, -0.18477343022823334f, -0.09105003625154495f, 0.0f,
    0.07958029955625534f, 0.16093020141124725f, 0.24611230194568634f,
    0.33791524171829224f, 0.44070982933044434f, 0.5626170039176941f,
    0.7229568362236023f, 1.0f};

__device__ __forceinline__ ushort f2h(float f) {
  return __half_as_ushort(__float2half(f));
}

// async global->LDS, 16B per lane; lds base wave-uniform + lane*16
__device__ __forceinline__ void async_cp16(const void* g, void* l) {
  __builtin_amdgcn_global_load_lds(
      (const __attribute__((address_space(1))) uint*)g,
      (__attribute__((address_space(3))) uint*)l, 16, 0, 0);
}

// table value via VGPR crossbar (conflict-free); lanes 0..15 of every 16 hold the table
__device__ __forceinline__ float nf4v(int c, int tbits) {
  return __int_as_float(__builtin_amdgcn_ds_bpermute(c << 2, tbits));
}

// producer-visible LDS + workgroup barrier, NO vmcnt drain (A loads are
// register-targeted; in-flight VMEM may span barriers = counted-vmcnt pipeline)
__device__ __forceinline__ void step_barrier() {
  asm volatile("s_waitcnt lgkmcnt(0)" ::: "memory");
  __builtin_amdgcn_s_barrier();
}

// kernel 1: pack q codes int32 -> 4-bit nibbles (8 codes/u32);
// x fp32 -> f16 in MFMA-fragment layout xf (16B frag f = ((kb*4+w)*8+(mt*2+ks2))*64 + lane);
// lora_B fp32 [OUTF,16] -> f16 [OUTF,64] zero-padded
__global__ void prep_kernel(const float* __restrict__ x, uint4* __restrict__ xf4,
                            const float4* __restrict__ lB4, ushort4* __restrict__ lBh4,
                            const int4* __restrict__ qc4, uint* __restrict__ q4) {
  const int stride = gridDim.x * blockDim.x;
  const int t0 = blockIdx.x * blockDim.x + threadIdx.x;
  // dominant loop: 180 MB read -> 22.5 MB write, pure streaming
  for (int i = t0; i < OUTF * (INF / 8); i += stride) {
    int4 a = qc4[(size_t)i * 2];
    int4 b = qc4[(size_t)i * 2 + 1];
    uint p = (uint)(a.x & 15) | ((uint)(a.y & 15) << 4) | ((uint)(a.z & 15) << 8) |
             ((uint)(a.w & 15) << 12) | ((uint)(b.x & 15) << 16) |
             ((uint)(b.y & 15) << 20) | ((uint)(b.z & 15) << 24) |
             ((uint)(b.w & 15) << 28);
    q4[i] = p;
  }
  // x -> fragment layout: one 16B frag per iteration (8 halfs along k of one row)
  for (int f = t0; f < TOK * INF / 8; f += stride) {
    int l = f & 63;
    int rlo = l & 15, chunk = l >> 4;
    int ms = (f >> 6) & 7;      // mt*2 + ks2
    int mt = ms >> 1, ks2 = ms & 1;
    int w = (f >> 9) & 3;
    int kb = f >> 11;
    int m = w * 64 + mt * 16 + rlo;
    int k0 = kb * 64 + (ks2 * 4 + chunk) * 8;
    const float4* src = (const float4*)(x + (size_t)m * INF + k0);
    float4 v0 = src[0], v1 = src[1];
    union { ushort4 h[2]; uint4 u; } pk;
    pk.h[0].x = f2h(v0.x); pk.h[0].y = f2h(v0.y); pk.h[0].z = f2h(v0.z); pk.h[0].w = f2h(v0.w);
    pk.h[1].x = f2h(v1.x); pk.h[1].y = f2h(v1.y); pk.h[1].z = f2h(v1.z); pk.h[1].w = f2h(v1.w);
    xf4[f] = pk.u;
  }
  for (int i = t0; i < OUTF * 16; i += stride) {
    int n = i >> 4, jq = i & 15;
    ushort4 o = {0, 0, 0, 0};
    if (jq < 4) {
      float4 v = lB4[n * 4 + jq];
      o.x = f2h(v.x); o.y = f2h(v.y); o.z = f2h(v.z); o.w = f2h(v.w);
    }
    lBh4[i] = o;
  }
}

// kernel 2: xa2[m][j] = f16( 2 * sum_k x[m][k]*lora_A[j][k] ), [TOK,64] zero-padded
__global__ __launch_bounds__(1024)
void xa_kernel(const float* __restrict__ x, const float* __restrict__ lA,
               ushort* __restrict__ xa2) {
  const int m = blockIdx.x;
  const int t = threadIdx.x;
  const float4* x4 = (const float4*)(x + (size_t)m * INF);
  const float4* lA4 = (const float4*)lA;
  float4 xv = x4[t];
  float acc[16];
#pragma unroll
  for (int j = 0; j < 16; ++j) {
    float4 a = lA4[j * (INF / 4) + t];
    acc[j] = xv.x * a.x + xv.y * a.y + xv.z * a.z + xv.w * a.w;
  }
#pragma unroll
  for (int j = 0; j < 16; ++j)
#pragma unroll
    for (int s = 32; s > 0; s >>= 1) acc[j] += __shfl_xor(acc[j], s, 64);
  __shared__ float red[16][16];
  const int w = t >> 6, l = t & 63;
  if (l == 0) {
#pragma unroll
    for (int j = 0; j < 16; ++j) red[w][j] = acc[j];
  }
  __syncthreads();
  if (t < 64) {
    ushort v = 0;
    if (t < 16) {
      float s = 0.f;
#pragma unroll
      for (int w2 = 0; w2 < 16; ++w2) s += red[w2][t];
      v = f2h(2.0f * s);
    }
    xa2[m * 64 + t] = v;
  }
}

// kernel 3: fused dequant GEMM, register-pipelined.
// A: direct global loads from pre-fragmented xf into double-buffered register
//    fragments (no LDS for A, no global_load_lds => no vmcnt drain at barriers).
// B: packed codes -> bpermute dequant -> double-buffered 8KB Bbuf (octet-swizzled).
// One raw s_barrier per K-step with lgkmcnt(0) only.
__global__ __launch_bounds__(256, 2)
void gemm_kernel(const uint* __restrict__ q4, const float* __restrict__ am,
                 const ushort* __restrict__ xf, const ushort* __restrict__ lBh,
                 const ushort* __restrict__ xa2, float* __restrict__ dest, int nst) {
  __shared__ ushort Bbuf[2][64 * 64];  // 2 x 8 KB, octet-swizzled
  __shared__ float Qax[4096];          // 16 KB: full absmax row per out-row [j][64 rows][4]

  const int tid = threadIdx.x;
  const int w = tid >> 6;
  const int l = tid & 63;
  const int chunk = l >> 4;  // 0..3
  const int rlo = l & 15;
  const int split = blockIdx.x / NT2;
  const int ntile = blockIdx.x - split * NT2;
  const int n0 = ntile * BN;
  const int kb0 = split * nst;  // in 64-k blocks

  const int tbits = __float_as_int(NF4_TBL[l & 15]);

  // packed-q geometry: thread owns row qr, octets oc2/oc2+1; uint2/step = 16 codes
  const int qr = tid >> 2;          // 0..63
  const int oc2 = (tid & 3) << 1;   // 0,2,4,6
  const uint* qb = q4 + (size_t)(n0 + qr) * (INF / 8) + (size_t)kb0 * 8 + oc2;
  const int bd0 = qr * 64 + ((oc2 ^ (qr & 7)) << 3);
  const int bd1 = qr * 64 + (((oc2 + 1) ^ (qr & 7)) << 3);

  // b-frag LDS read offsets (swizzle-matched)
  int boff[2][4];
#pragma unroll
  for (int ks2 = 0; ks2 < 2; ++ks2)
#pragma unroll
    for (int nt = 0; nt < 4; ++nt)
      boff[ks2][nt] = (nt * 16 + rlo) * 64 + (((ks2 * 4 + chunk) ^ (rlo & 7)) << 3);

  f32x4 acc[4][4];
#pragma unroll
  for (int mt = 0; mt < 4; ++mt)
#pragma unroll
    for (int nt = 0; nt < 4; ++nt) acc[mt][nt] = (f32x4){0.f, 0.f, 0.f, 0.f};

  // A fragment loads: coalesced 16B/lane from xf
  auto loadA = [&](f16x8 ar[2][4], int kb) {
    const ushort* base = xf + ((size_t)kb * 4 + w) * 4096 + (size_t)l * 8;
#pragma unroll
    for (int mt = 0; mt < 4; ++mt)
#pragma unroll
      for (int ks2 = 0; ks2 < 2; ++ks2)
        ar[ks2][mt] = *(const f16x8*)(base + (mt * 2 + ks2) * 512);
  };

  // dequant 16 codes of absolute k-block kbt -> target Bbuf
  auto dequantF = [&](uint2 q, int kbt, ushort* bb) {
    const __half2 ax2 = __float2half2_rn(Qax[(kbt >> 2) * 256 + qr * 4 + (kbt & 3)]);
    const uint q0 = q.x, q1 = q.y;
    union { __half2 h[4]; uint4 u; } r0, r1;
    r0.h[0] = __hmul2(__floats2half2_rn(nf4v(q0 & 15, tbits), nf4v((q0 >> 4) & 15, tbits)), ax2);
    r0.h[1] = __hmul2(__floats2half2_rn(nf4v((q0 >> 8) & 15, tbits), nf4v((q0 >> 12) & 15, tbits)), ax2);
    r0.h[2] = __hmul2(__floats2half2_rn(nf4v((q0 >> 16) & 15, tbits), nf4v((q0 >> 20) & 15, tbits)), ax2);
    r0.h[3] = __hmul2(__floats2half2_rn(nf4v((q0 >> 24) & 15, tbits), nf4v(q0 >> 28, tbits)), ax2);
    r1.h[0] = __hmul2(__floats2half2_rn(nf4v(q1 & 15, tbits), nf4v((q1 >> 4) & 15, tbits)), ax2);
    r1.h[1] = __hmul2(__floats2half2_rn(nf4v((q1 >> 8) & 15, tbits), nf4v((q1 >> 12) & 15, tbits)), ax2);
    r1.h[2] = __hmul2(__floats2half2_rn(nf4v((q1 >> 16) & 15, tbits), nf4v((q1 >> 20) & 15, tbits)), ax2);
    r1.h[3] = __hmul2(__floats2half2_rn(nf4v((q1 >> 24) & 15, tbits), nf4v(q1 >> 28, tbits)), ax2);
    *(uint4*)&bb[bd0] = r0.u;
    *(uint4*)&bb[bd1] = r1.u;
  };

  auto compute = [&](f16x8 ar[2][4], const ushort* bb) {
    __builtin_amdgcn_s_setprio(1);
#pragma unroll
    for (int ks2 = 0; ks2 < 2; ++ks2) {
      f16x8 b[4];
#pragma unroll
      for (int nt = 0; nt < 4; ++nt) b[nt] = *(const f16x8*)&bb[boff[ks2][nt]];
#pragma unroll
      for (int mt = 0; mt < 4; ++mt)
#pragma unroll
        for (int nt = 0; nt < 4; ++nt)
          acc[mt][nt] = __builtin_amdgcn_mfma_f32_16x16x32_f16(ar[ks2][mt], b[nt], acc[mt][nt], 0, 0, 0);
    }
    __builtin_amdgcn_s_setprio(0);
  };

  // prologue: Qax full row via DMA; A(0),A(1),q(0),q(1) into registers
  if (w == 0) {
#pragma unroll
    for (int j = 0; j < 16; ++j)
      async_cp16(am + (size_t)(n0 + l) * 64 + j * 4, (char*)Qax + j * 1024);
  }
  f16x8 arA[2][4], arB[2][4];
  loadA(arA, kb0);
  loadA(arB, kb0 + 1);
  uint2 qA = *(const uint2*)qb;
  uint2 qB = *(const uint2*)(qb + 8);
  __syncthreads();  // drains Qax DMA (vmcnt+lgkm), once
  dequantF(qA, kb0, Bbuf[0]);
  step_barrier();

  // main loop: nst even (16/8/32/64); B(t) lives in Bbuf[t&1]
  for (int s = 0; s < nst; s += 2) {
    // even step: compute A(s)*B(s); produce B(s+1); refill A(s+2),q(s+2)
    compute(arA, Bbuf[0]);
    if (s + 1 < nst) dequantF(qB, kb0 + s + 1, Bbuf[1]);
    if (s + 2 < nst) {
      loadA(arA, kb0 + s + 2);
      qA = *(const uint2*)(qb + (size_t)(s + 2) * 8);
    }
    step_barrier();
    // odd step
    compute(arB, Bbuf[1]);
    if (s + 2 < nst) dequantF(qA, kb0 + s + 2, Bbuf[0]);
    if (s + 3 < nst) {
      loadA(arB, kb0 + s + 3);
      qB = *(const uint2*)(qb + (size_t)(s + 3) * 8);
    }
    step_barrier();
  }

  if (split == 0) {
    // lora K-extension: k in [0,32) (rank 16 + zero pad); direct register frags
    f16x8 a_l[4], b_l[4];
#pragma unroll
    for (int mt = 0; mt < 4; ++mt)
      a_l[mt] = *(const f16x8*)(xa2 + (size_t)(w * 64 + mt * 16 + rlo) * 64 + chunk * 8);
#pragma unroll
    for (int nt = 0; nt < 4; ++nt)
      b_l[nt] = *(const f16x8*)(lBh + (size_t)(n0 + nt * 16 + rlo) * 64 + chunk * 8);
#pragma unroll
    for (int mt = 0; mt < 4; ++mt)
#pragma unroll
      for (int nt = 0; nt < 4; ++nt)
        acc[mt][nt] = __builtin_amdgcn_mfma_f32_16x16x32_f16(a_l[mt], b_l[nt], acc[mt][nt], 0, 0, 0);
  }

  // epilogue: C/D layout col=lane&15, row=(lane>>4)*4+reg; each split owns a slice
  float* dst = dest + (size_t)split * TOK * OUTF;
#pragma unroll
  for (int mt = 0; mt < 4; ++mt) {
#pragma unroll
    for (int nt = 0; nt < 4; ++nt) {
      int c = n0 + nt * 16 + rlo;
#pragma unroll
      for (int r = 0; r < 4; ++r) {
        int row = w * 64 + mt * 16 + chunk * 4 + r;
        dst[(size_t)row * OUTF + c] = acc[mt][nt][r];
      }
    }
  }
}

// kernel 4: sum K-split partials -> out
__global__ void reduce_kernel(const float4* __restrict__ part, float4* __restrict__ out,
                              int ks) {
  const int QN = TOK * OUTF / 4;
  int i = blockIdx.x * blockDim.x + threadIdx.x;
  if (i < QN) {
    float4 s = part[i];
    for (int s2 = 1; s2 < ks; ++s2) {
      float4 p = part[(size_t)s2 * QN + i];
      s.x += p.x; s.y += p.y; s.z += p.z; s.w += p.w;
    }
    out[i] = s;
  }
}

extern "C" void kernel_launch(void* const* d_in, const int* in_sizes, int n_in,
                              void* d_out, int out_size, void* d_ws, size_t ws_size,
                              hipStream_t stream) {
  const float* x = (const float*)d_in[0];
  const int* qc = (const int*)d_in[1];
  const float* am = (const float*)d_in[2];
  const float* lA = (const float*)d_in[3];
  const float* lB = (const float*)d_in[4];
  float* out = (float*)d_out;

  const size_t off_lB = (size_t)TOK * INF * 2;              // 2.10 MB (xf)
  const size_t off_xa2 = off_lB + (size_t)OUTF * 64 * 2;    // +1.41 MB
  const size_t off_q4 = off_xa2 + (size_t)TOK * 64 * 2;     // +32 KB
  const size_t off_part = off_q4 + (size_t)OUTF * (INF / 8) * 4;  // +22.5 MB
  const size_t part_bytes = (size_t)TOK * OUTF * 4;         // 11.27 MB per split

  ushort* xf = (ushort*)d_ws;
  ushort* lBh = (ushort*)((char*)d_ws + off_lB);
  ushort* xa2 = (ushort*)((char*)d_ws + off_xa2);
  uint* q4 = (uint*)((char*)d_ws + off_q4);
  float* part = (float*)((char*)d_ws + off_part);

  int ks = 1;
  if (ws_size >= off_part + 4 * part_bytes) ks = 4;  // ws ~688 MB observed -> ks=4
  else if (ws_size >= off_part + 2 * part_bytes) ks = 2;
  float* dest = (ks == 1) ? out : part;

  prep_kernel<<<2048, 256, 0, stream>>>(x, (uint4*)xf, (const float4*)lB,
                                        (ushort4*)lBh, (const int4*)qc, q4);
  xa_kernel<<<TOK, 1024, 0, stream>>>(x, lA, xa2);
  gemm_kernel<<<NT2 * ks, 256, 0, stream>>>(q4, am, xf, lBh, xa2, dest, 64 / ks);
  if (ks > 1)
    reduce_kernel<<<(TOK * OUTF / 4 + 255) / 256, 256, 0, stream>>>((const float4*)part,
                                                                    (float4*)out, ks);
}

// Round 3
// 318.244 us; speedup vs baseline: 1.0287x; 1.0287x over previous
//
#include <hip/hip_runtime.h>
#include <hip/hip_fp16.h>

typedef unsigned int uint;
typedef unsigned short ushort;

typedef __attribute__((ext_vector_type(8))) _Float16 f16x8;
typedef __attribute__((ext_vector_type(4))) float f32x4;

#define TOK 256
#define OUTF 11008
#define INF 4096
#define BM 256
#define BN 64
#define NT2 172  // OUTF / BN

__device__ __constant__ float NF4_TBL[16] = {
    -1.0f, -0.6961928009986877f, -0.5250730514526367f, -0.39491748809814453f,
    -0.28444138169288635f, -0.18477343022823334f, -0.09105003625154495f, 0.0f,
    0.07958029955625534f, 0.16093020141124725f, 0.24611230194568634f,
    0.33791524171829224f, 0.44070982933044434f, 0.5626170039176941f,
    0.7229568362236023f, 1.0f};

__device__ __forceinline__ ushort f2h(float f) {
  return __half_as_ushort(__float2half(f));
}

// async global->LDS, 16B per lane; lds base wave-uniform + lane*16
__device__ __forceinline__ void async_cp16(const void* g, void* l) {
  __builtin_amdgcn_global_load_lds(
      (const __attribute__((address_space(1))) uint*)g,
      (__attribute__((address_space(3))) uint*)l, 16, 0, 0);
}

// table value via VGPR crossbar (conflict-free); lanes 0..15 of every 16 hold the table
__device__ __forceinline__ float nf4v(int c, int tbits) {
  return __int_as_float(__builtin_amdgcn_ds_bpermute(c << 2, tbits));
}

// 4 raw codes -> 4 scaled halfs (8B)
__device__ __forceinline__ uint2 dq4(int4 c, __half2 ax2, int tbits) {
  __half2 h0 = __floats2half2_rn(nf4v(c.x, tbits), nf4v(c.y, tbits));
  __half2 h1 = __floats2half2_rn(nf4v(c.z, tbits), nf4v(c.w, tbits));
  h0 = __hmul2(h0, ax2);
  h1 = __hmul2(h1, ax2);
  union { __half2 h[2]; uint2 u; } r;
  r.h[0] = h0; r.h[1] = h1;
  return r.u;
}

// LDS-visibility barrier, NO vmcnt drain (global loads target registers and
// may stay in flight across the barrier = counted-vmcnt pipeline)
__device__ __forceinline__ void step_barrier() {
  asm volatile("s_waitcnt lgkmcnt(0)" ::: "memory");
  __builtin_amdgcn_s_barrier();
}

// kernel 1: x fp32 -> f16 in MFMA-fragment layout xf
// (16B frag f = ((kb*4+w)*8+(mt*2+ks2))*64 + lane); lora_B fp32 [OUTF,16] -> f16
// [OUTF,64] zero-padded. Raw q codes go straight to the gemm (latency-hidden there).
__global__ void prep_kernel(const float* __restrict__ x, uint4* __restrict__ xf4,
                            const float4* __restrict__ lB4, ushort4* __restrict__ lBh4) {
  const int stride = gridDim.x * blockDim.x;
  const int t0 = blockIdx.x * blockDim.x + threadIdx.x;
  // x -> fragment layout: one 16B frag per iteration (8 halfs along k of one row)
  for (int f = t0; f < TOK * INF / 8; f += stride) {
    int l = f & 63;
    int rlo = l & 15, chunk = l >> 4;
    int ms = (f >> 6) & 7;      // mt*2 + ks2
    int mt = ms >> 1, ks2 = ms & 1;
    int w = (f >> 9) & 3;
    int kb = f >> 11;
    int m = w * 64 + mt * 16 + rlo;
    int k0 = kb * 64 + (ks2 * 4 + chunk) * 8;
    const float4* src = (const float4*)(x + (size_t)m * INF + k0);
    float4 v0 = src[0], v1 = src[1];
    union { ushort4 h[2]; uint4 u; } pk;
    pk.h[0].x = f2h(v0.x); pk.h[0].y = f2h(v0.y); pk.h[0].z = f2h(v0.z); pk.h[0].w = f2h(v0.w);
    pk.h[1].x = f2h(v1.x); pk.h[1].y = f2h(v1.y); pk.h[1].z = f2h(v1.z); pk.h[1].w = f2h(v1.w);
    xf4[f] = pk.u;
  }
  for (int i = t0; i < OUTF * 16; i += stride) {
    int n = i >> 4, jq = i & 15;
    ushort4 o = {0, 0, 0, 0};
    if (jq < 4) {
      float4 v = lB4[n * 4 + jq];
      o.x = f2h(v.x); o.y = f2h(v.y); o.z = f2h(v.z); o.w = f2h(v.w);
    }
    lBh4[i] = o;
  }
}

// kernel 2: xa2[m][j] = f16( 2 * sum_k x[m][k]*lora_A[j][k] ), [TOK,64] zero-padded
__global__ __launch_bounds__(1024)
void xa_kernel(const float* __restrict__ x, const float* __restrict__ lA,
               ushort* __restrict__ xa2) {
  const int m = blockIdx.x;
  const int t = threadIdx.x;
  const float4* x4 = (const float4*)(x + (size_t)m * INF);
  const float4* lA4 = (const float4*)lA;
  float4 xv = x4[t];
  float acc[16];
#pragma unroll
  for (int j = 0; j < 16; ++j) {
    float4 a = lA4[j * (INF / 4) + t];
    acc[j] = xv.x * a.x + xv.y * a.y + xv.z * a.z + xv.w * a.w;
  }
#pragma unroll
  for (int j = 0; j < 16; ++j)
#pragma unroll
    for (int s = 32; s > 0; s >>= 1) acc[j] += __shfl_xor(acc[j], s, 64);
  __shared__ float red[16][16];
  const int w = t >> 6, l = t & 63;
  if (l == 0) {
#pragma unroll
    for (int j = 0; j < 16; ++j) red[w][j] = acc[j];
  }
  __syncthreads();
  if (t < 64) {
    ushort v = 0;
    if (t < 16) {
      float s = 0.f;
#pragma unroll
      for (int w2 = 0; w2 < 16; ++w2) s += red[w2][t];
      v = f2h(2.0f * s);
    }
    xa2[m * 64 + t] = v;
  }
}

// kernel 3: fused dequant GEMM, register-pipelined.
// A: direct global loads from pre-fragmented xf into double-buffered register
//    fragments (no LDS for A, no global_load_lds => no vmcnt drain at barriers).
// Codes: RAW int32 qc, coalesced int4 loads, double-buffered registers with
//    2-step prefetch depth (the one-time 180 MB read rides the latency-tolerant
//    pipeline instead of a dedicated streaming pass — R1's pack was net-negative).
// B: bpermute dequant -> double-buffered 8KB Bbuf (octet-swizzled).
// One raw s_barrier per K-step with lgkmcnt(0) only.
__global__ __launch_bounds__(256, 2)
void gemm_kernel(const int* __restrict__ qc, const float* __restrict__ am,
                 const ushort* __restrict__ xf, const ushort* __restrict__ lBh,
                 const ushort* __restrict__ xa2, float* __restrict__ dest, int nst) {
  __shared__ ushort Bbuf[2][64 * 64];  // 2 x 8 KB, octet-swizzled
  __shared__ float Qax[4096];          // 16 KB: full absmax rows [kb>>2][64 rows][kb&3]

  const int tid = threadIdx.x;
  const int w = tid >> 6;
  const int l = tid & 63;
  const int chunk = l >> 4;  // 0..3
  const int rlo = l & 15;
  const int split = blockIdx.x / NT2;
  const int ntile = blockIdx.x - split * NT2;
  const int n0 = ntile * BN;
  const int kb0 = split * nst;  // in 64-k blocks

  const int tbits = __float_as_int(NF4_TBL[l & 15]);

  // raw-q geometry (coalesced, proven R0): per pass p, row r = p*16 + (tid>>4),
  // chunk qch = tid&15 -> int4 = 4 codes
  const int qrg = tid >> 4;  // 0..15
  const int qch = tid & 15;  // 0..15
  const int* qbase[4];
  int bdst[4];
#pragma unroll
  for (int p = 0; p < 4; ++p) {
    int r = p * 16 + qrg;
    qbase[p] = qc + (size_t)(n0 + r) * INF + kb0 * 64 + qch * 4;
    bdst[p] = r * 64 + (((qch >> 1) ^ (r & 7)) << 3) + (qch & 1) * 4;
  }

  // b-frag LDS read offsets (swizzle-matched)
  int boff[2][4];
#pragma unroll
  for (int ks2 = 0; ks2 < 2; ++ks2)
#pragma unroll
    for (int nt = 0; nt < 4; ++nt)
      boff[ks2][nt] = (nt * 16 + rlo) * 64 + (((ks2 * 4 + chunk) ^ (rlo & 7)) << 3);

  f32x4 acc[4][4];
#pragma unroll
  for (int mt = 0; mt < 4; ++mt)
#pragma unroll
    for (int nt = 0; nt < 4; ++nt) acc[mt][nt] = (f32x4){0.f, 0.f, 0.f, 0.f};

  // A fragment loads: coalesced 16B/lane from xf (L2-resident, 2 MB)
  auto loadA = [&](f16x8 ar[2][4], int kb) {
    const ushort* base = xf + ((size_t)kb * 4 + w) * 4096 + (size_t)l * 8;
#pragma unroll
    for (int mt = 0; mt < 4; ++mt)
#pragma unroll
      for (int ks2 = 0; ks2 < 2; ++ks2)
        ar[ks2][mt] = *(const f16x8*)(base + (mt * 2 + ks2) * 512);
  };

  auto loadQ = [&](int4 q[4], int s) {
#pragma unroll
    for (int p = 0; p < 4; ++p) q[p] = *(const int4*)(qbase[p] + (size_t)s * 64);
  };

  // dequant 16 codes of absolute k-block kbt -> target Bbuf
  auto dequantF = [&](int4 q[4], int kbt, ushort* bb) {
#pragma unroll
    for (int p = 0; p < 4; ++p) {
      int r = p * 16 + qrg;
      __half2 ax2 = __float2half2_rn(Qax[(kbt >> 2) * 256 + r * 4 + (kbt & 3)]);
      *(uint2*)&bb[bdst[p]] = dq4(q[p], ax2, tbits);
    }
  };

  auto compute = [&](f16x8 ar[2][4], const ushort* bb) {
    __builtin_amdgcn_s_setprio(1);
#pragma unroll
    for (int ks2 = 0; ks2 < 2; ++ks2) {
      f16x8 b[4];
#pragma unroll
      for (int nt = 0; nt < 4; ++nt) b[nt] = *(const f16x8*)&bb[boff[ks2][nt]];
#pragma unroll
      for (int mt = 0; mt < 4; ++mt)
#pragma unroll
        for (int nt = 0; nt < 4; ++nt)
          acc[mt][nt] = __builtin_amdgcn_mfma_f32_16x16x32_f16(ar[ks2][mt], b[nt], acc[mt][nt], 0, 0, 0);
    }
    __builtin_amdgcn_s_setprio(0);
  };

  // prologue: Qax full rows via DMA; A(0),A(1),q(0),q(1) into registers
  if (w == 0) {
#pragma unroll
    for (int j = 0; j < 16; ++j)
      async_cp16(am + (size_t)(n0 + l) * 64 + j * 4, (char*)Qax + j * 1024);
  }
  f16x8 arA[2][4], arB[2][4];
  int4 qA[4], qB[4];
  loadA(arA, kb0);
  loadA(arB, kb0 + 1);
  loadQ(qA, 0);
  loadQ(qB, 1);
  __syncthreads();  // drains Qax DMA (vmcnt+lgkm), once
  dequantF(qA, kb0, Bbuf[0]);
  step_barrier();

  // main loop: nst even (16/8/32/64); B(t) lives in Bbuf[t&1]
  for (int s = 0; s < nst; s += 2) {
    // even step: compute A(s)*B(s); produce B(s+1); refill A(s+2),q(s+2)
    compute(arA, Bbuf[0]);
    if (s + 1 < nst) dequantF(qB, kb0 + s + 1, Bbuf[1]);
    if (s + 2 < nst) {
      loadA(arA, kb0 + s + 2);
      loadQ(qA, s + 2);
    }
    step_barrier();
    // odd step
    compute(arB, Bbuf[1]);
    if (s + 2 < nst) dequantF(qA, kb0 + s + 2, Bbuf[0]);
    if (s + 3 < nst) {
      loadA(arB, kb0 + s + 3);
      loadQ(qB, s + 3);
    }
    step_barrier();
  }

  if (split == 0) {
    // lora K-extension: k in [0,32) (rank 16 + zero pad); direct register frags
    f16x8 a_l[4], b_l[4];
#pragma unroll
    for (int mt = 0; mt < 4; ++mt)
      a_l[mt] = *(const f16x8*)(xa2 + (size_t)(w * 64 + mt * 16 + rlo) * 64 + chunk * 8);
#pragma unroll
    for (int nt = 0; nt < 4; ++nt)
      b_l[nt] = *(const f16x8*)(lBh + (size_t)(n0 + nt * 16 + rlo) * 64 + chunk * 8);
#pragma unroll
    for (int mt = 0; mt < 4; ++mt)
#pragma unroll
      for (int nt = 0; nt < 4; ++nt)
        acc[mt][nt] = __builtin_amdgcn_mfma_f32_16x16x32_f16(a_l[mt], b_l[nt], acc[mt][nt], 0, 0, 0);
  }

  // epilogue: C/D layout col=lane&15, row=(lane>>4)*4+reg; each split owns a slice
  float* dst = dest + (size_t)split * TOK * OUTF;
#pragma unroll
  for (int mt = 0; mt < 4; ++mt) {
#pragma unroll
    for (int nt = 0; nt < 4; ++nt) {
      int c = n0 + nt * 16 + rlo;
#pragma unroll
      for (int r = 0; r < 4; ++r) {
        int row = w * 64 + mt * 16 + chunk * 4 + r;
        dst[(size_t)row * OUTF + c] = acc[mt][nt][r];
      }
    }
  }
}

// kernel 4: sum K-split partials -> out
__global__ void reduce_kernel(const float4* __restrict__ part, float4* __restrict__ out,
                              int ks) {
  const int QN = TOK * OUTF / 4;
  int i = blockIdx.x * blockDim.x + threadIdx.x;
  if (i < QN) {
    float4 s = part[i];
    for (int s2 = 1; s2 < ks; ++s2) {
      float4 p = part[(size_t)s2 * QN + i];
      s.x += p.x; s.y += p.y; s.z += p.z; s.w += p.w;
    }
    out[i] = s;
  }
}

extern "C" void kernel_launch(void* const* d_in, const int* in_sizes, int n_in,
                              void* d_out, int out_size, void* d_ws, size_t ws_size,
                              hipStream_t stream) {
  const float* x = (const float*)d_in[0];
  const int* qc = (const int*)d_in[1];
  const float* am = (const float*)d_in[2];
  const float* lA = (const float*)d_in[3];
  const float* lB = (const float*)d_in[4];
  float* out = (float*)d_out;

  const size_t off_lB = (size_t)TOK * INF * 2;              // 2.10 MB (xf)
  const size_t off_xa2 = off_lB + (size_t)OUTF * 64 * 2;    // +1.41 MB
  const size_t off_part = off_xa2 + (size_t)TOK * 64 * 2;   // +32 KB
  const size_t part_bytes = (size_t)TOK * OUTF * 4;         // 11.27 MB per split

  ushort* xf = (ushort*)d_ws;
  ushort* lBh = (ushort*)((char*)d_ws + off_lB);
  ushort* xa2 = (ushort*)((char*)d_ws + off_xa2);
  float* part = (float*)((char*)d_ws + off_part);

  int ks = 1;
  if (ws_size >= off_part + 4 * part_bytes) ks = 4;  // ws ~688 MB observed -> ks=4
  else if (ws_size >= off_part + 2 * part_bytes) ks = 2;
  float* dest = (ks == 1) ? out : part;

  prep_kernel<<<2048, 256, 0, stream>>>(x, (uint4*)xf, (const float4*)lB,
                                        (ushort4*)lBh);
  xa_kernel<<<TOK, 1024, 0, stream>>>(x, lA, xa2);
  gemm_kernel<<<NT2 * ks, 256, 0, stream>>>(qc, am, xf, lBh, xa2, dest, 64 / ks);
  if (ks > 1)
    reduce_kernel<<<(TOK * OUTF / 4 + 255) / 256, 256, 0, stream>>>((const float4*)part,
                                                                    (float4*)out, ks);
}